// Round 13
// baseline (174.877 us; speedup 1.0000x reference)
//
#include <hip/hip_runtime.h>
#include <hip/hip_bf16.h>

typedef __bf16 bf16x8 __attribute__((ext_vector_type(8)));
typedef float f32x4 __attribute__((ext_vector_type(4)));
typedef unsigned int u32;
typedef u32 u32x4 __attribute__((ext_vector_type(4)));

#define MFMA(a, b, c) __builtin_amdgcn_mfma_f32_16x16x32_bf16((a), (b), (c), 0, 0, 0)

static __device__ __forceinline__ bf16x8 ld8(const __bf16* p) {
  return *reinterpret_cast<const bf16x8*>(p);
}

// pack two f32 -> bf16x2 in one u32 (compiler fuses to v_cvt_pk_bf16_f32)
static __device__ __forceinline__ u32 pkbf(float a, float b) {
  union { __bf16 h; unsigned short s; } x, y;
  x.h = (__bf16)a; y.h = (__bf16)b;
  return (u32)x.s | ((u32)y.s << 16);
}

// async global->LDS, 16B per lane; LDS dest is wave-uniform base + lane*16
typedef unsigned int __attribute__((address_space(1))) gu32_t;
typedef unsigned int __attribute__((address_space(3))) lu32_t;
static __device__ __forceinline__ void gld16(const __bf16* g, __bf16* l) {
  __builtin_amdgcn_global_load_lds((const gu32_t*)(const void*)g,
                                   (lu32_t*)(void*)l, 16, 0, 0);
}

// fp32 -> bf16 conversion for x and W_qkv (exact-fit into d_out region)
__global__ __launch_bounds__(256)
void cvt_f32_bf16(const float* __restrict__ a, __bf16* __restrict__ oa, int na,
                  const float* __restrict__ b, __bf16* __restrict__ ob) {
  const int i = blockIdx.x * 256 + threadIdx.x;  // one 8-elem chunk per thread
  const float* src; __bf16* dst; int e;
  if (i < (na >> 3)) { src = a; dst = oa; e = i << 3; }
  else { src = b; dst = ob; e = (i << 3) - na; }
  f32x4 v0 = *reinterpret_cast<const f32x4*>(src + e);
  f32x4 v1 = *reinterpret_cast<const f32x4*>(src + e + 4);
  bf16x8 o;
#pragma unroll
  for (int j = 0; j < 4; ++j) { o[j] = (__bf16)v0[j]; o[j + 4] = (__bf16)v1[j]; }
  *reinterpret_cast<bf16x8*>(dst + e) = o;
}

// 8 fp32 -> 8 bf16 LDS write (16B)
static __device__ __forceinline__ void stage8f(__bf16* __restrict__ dst,
                                               const float* __restrict__ src) {
  f32x4 a = *reinterpret_cast<const f32x4*>(src);
  f32x4 b = *reinterpret_cast<const f32x4*>(src + 4);
  bf16x8 o;
#pragma unroll
  for (int i = 0; i < 4; ++i) { o[i] = (__bf16)a[i]; o[i + 4] = (__bf16)b[i]; }
  *reinterpret_cast<bf16x8*>(dst) = o;
}

// C[m][n] = sum_k A[m][k] * W[n][k]  (A @ W^T).  BM=128, BK=64, BN template.
// A bf16 via global_load_lds(16B), pre-swizzled source (chunk ^= row&7).
// W: bf16 via gld16 (same swizzle) or fp32 via reg-stage + swizzled ds_write.
// 4 waves 2x2; wave tile 64 x BN/2. SPLIT (GEMM1): Q cols scaled by SC2Q;
// cols [0,2048) -> QK buf; [2048,3072) -> VT[b*1024+col-2048][t].
template<int BN, bool SPLIT, bool OUT_BF16, bool B_F32>
__global__ __launch_bounds__(256, 2)
void gemm3(const __bf16* __restrict__ A, const void* __restrict__ Wv,
           void* __restrict__ Cv, __bf16* __restrict__ VT,
           int M, int N, int K) {
  constexpr int NF = BN / 32;  // B frags per wave per kc
  constexpr float SC2Q = 0.125f * 1.4426950408889634f;
  __shared__ __bf16 lA[128 * 64];
  __shared__ __bf16 lB[BN * 64];

  const int tid = threadIdx.x;
  const int ntiles = N / BN;
  const int mt = blockIdx.x / ntiles;
  const int nt = blockIdx.x % ntiles;
  const int m0 = mt << 7, n0 = nt * BN;
  const int lane = tid & 63, w = tid >> 6;
  const int wm = (w >> 1) << 6;
  const int wn = (w & 1) * (BN / 2);
  const int fr = lane & 15, fg = lane >> 4;

  f32x4 acc[4][NF] = {};

  for (int k0 = 0; k0 < K; k0 += 64) {
    __syncthreads();
#pragma unroll
    for (int jj = 0; jj < 4; ++jj) {
      const int q = (w << 2) | jj;
      const int v = (q << 6) | lane;
      const int row = v >> 3;
      const int cc = (v & 7) ^ (row & 7);
      gld16(A + (size_t)(m0 + row) * K + k0 + (cc << 3), lA + (q << 9));
    }
    if constexpr (B_F32) {
#pragma unroll
      for (int hh = 0; hh < BN / 64; ++hh) {
        const int row = (tid >> 2) + (hh << 6);
        const int c0 = (tid & 3) << 1;
        const float* src = (const float*)Wv + (size_t)(n0 + row) * K + k0 + (c0 << 3);
#pragma unroll
        for (int cg = 0; cg < 2; ++cg)
          stage8f(lB + (row << 6) + (((c0 + cg) ^ (row & 7)) << 3), src + (cg << 3));
      }
    } else {
#pragma unroll
      for (int jj = 0; jj < NF; ++jj) {
        const int q = w * NF + jj;
        const int v = (q << 6) | lane;
        const int row = v >> 3;
        const int cc = (v & 7) ^ (row & 7);
        gld16((const __bf16*)Wv + (size_t)(n0 + row) * K + k0 + (cc << 3), lB + (q << 9));
      }
    }
    __syncthreads();

    bf16x8 af[2][4], bfr[2][NF];
#pragma unroll
    for (int kc = 0; kc < 2; ++kc) {
#pragma unroll
      for (int m = 0; m < 4; ++m) {
        const int row = wm + m * 16 + fr;
        af[kc][m] = ld8(lA + (row << 6) + ((((kc << 2) | fg) ^ (row & 7)) << 3));
      }
#pragma unroll
      for (int n = 0; n < NF; ++n) {
        const int row = wn + n * 16 + fr;
        bfr[kc][n] = ld8(lB + (row << 6) + ((((kc << 2) | fg) ^ (row & 7)) << 3));
      }
    }
#pragma unroll
    for (int kc = 0; kc < 2; ++kc)
#pragma unroll
      for (int m = 0; m < 4; ++m)
#pragma unroll
        for (int n = 0; n < NF; ++n)
          acc[m][n] = MFMA(af[kc][m], bfr[kc][n], acc[m][n]);
  }

  // C/D layout: col = lane&15, row = (lane>>4)*4 + reg
#pragma unroll
  for (int m = 0; m < 4; ++m) {
#pragma unroll
    for (int n = 0; n < NF; ++n) {
#pragma unroll
      for (int r = 0; r < 4; ++r) {
        int row = m0 + wm + m * 16 + fg * 4 + r;
        int col = n0 + wn + n * 16 + fr;
        float v = acc[m][n][r];
        if constexpr (SPLIT) {
          int b = row >> 11, t = row & 2047;
          if (col >= 2048) {
            VT[((size_t)(b << 10) + (col - 2048)) * 2048 + t] = (__bf16)v;
          } else {
            if (col < 1024) v *= SC2Q;  // pre-scale Q for attention
            ((__bf16*)Cv)[(size_t)row * 2048 + col] = (__bf16)v;
          }
        } else if constexpr (OUT_BF16) {
          ((__bf16*)Cv)[(size_t)row * N + col] = (__bf16)v;
        } else {
          ((float*)Cv)[(size_t)row * N + col] = v;
        }
      }
    }
  }
}

// One online-softmax step for a 64-key tile held as S^T fragments.
// s[n][r] = S[key=k0+n*16+fg*4+r][q=q0wt+fr] (already scaled, log2 domain).
static __device__ __forceinline__ void softmax_step(
    f32x4 (&s)[4], f32x4 (&o)[4], float& m, float& l, bf16x8 (&pa)[2],
    bool diag, int q0wt, int k0, int fg, int fr) {
  constexpr float NEG = -1e30f;
  float sv[4][4];
#pragma unroll
  for (int n = 0; n < 4; ++n)
#pragma unroll
    for (int r = 0; r < 4; ++r) {
      float x = s[n][r];
      if (diag && (k0 + n * 16 + fg * 4 + r > q0wt + fr)) x = NEG;
      sv[n][r] = x;
    }

  float t0 = fmaxf(fmaxf(sv[0][0], sv[0][1]), fmaxf(sv[0][2], sv[0][3]));
  float t1 = fmaxf(fmaxf(sv[1][0], sv[1][1]), fmaxf(sv[1][2], sv[1][3]));
  float t2 = fmaxf(fmaxf(sv[2][0], sv[2][1]), fmaxf(sv[2][2], sv[2][3]));
  float t3 = fmaxf(fmaxf(sv[3][0], sv[3][1]), fmaxf(sv[3][2], sv[3][3]));
  float rm = fmaxf(fmaxf(t0, t1), fmaxf(t2, t3));
  rm = fmaxf(rm, __shfl_xor(rm, 16));
  rm = fmaxf(rm, __shfl_xor(rm, 32));

  // defer-max (T13): rescale only when tile max pushes past m+16
  if (!__all(rm <= m + 16.f)) {
    float mnew = fmaxf(m, rm);
    float alpha = __builtin_exp2f(m - mnew);
    m = mnew;
    l *= alpha;
    float ao[4];
#pragma unroll
    for (int r = 0; r < 4; ++r)
      ao[r] = __shfl(alpha, fg * 4 + r);
#pragma unroll
    for (int n = 0; n < 4; ++n)
#pragma unroll
      for (int r = 0; r < 4; ++r)
        o[n][r] *= ao[r];
  }

  float p[4][4];
#pragma unroll
  for (int n = 0; n < 4; ++n)
#pragma unroll
    for (int r = 0; r < 4; ++r)
      p[n][r] = __builtin_exp2f(sv[n][r] - m);

  float u0 = (p[0][0] + p[0][1]) + (p[0][2] + p[0][3]);
  float u1 = (p[1][0] + p[1][1]) + (p[1][2] + p[1][3]);
  float u2 = (p[2][0] + p[2][1]) + (p[2][2] + p[2][3]);
  float u3 = (p[3][0] + p[3][1]) + (p[3][2] + p[3][3]);
  float rs = (u0 + u1) + (u2 + u3);
  rs += __shfl_xor(rs, 16);
  rs += __shfl_xor(rs, 32);
  l += rs;

  u32 wpk[4][2];
#pragma unroll
  for (int n = 0; n < 4; ++n) {
    wpk[n][0] = pkbf(p[n][0], p[n][1]);
    wpk[n][1] = pkbf(p[n][2], p[n][3]);
  }

  // redistribute P^T -> PV A-fragments (8 bpermutes; bijective instances)
  u32 rcv[2][2][2];
#pragma unroll
  for (int e = 0; e < 2; ++e) {
    const int src = fr + ((((fg & 1) << 1) | ((fg >> 1) ^ e)) << 4);
    const bool tsel = ((fg & 1) ^ e) != 0;
#pragma unroll
    for (int c = 0; c < 2; ++c)
#pragma unroll
      for (int hh = 0; hh < 2; ++hh) {
        u32 v = tsel ? wpk[(c << 1) | 1][hh] : wpk[(c << 1) | 0][hh];
        rcv[e][c][hh] = (u32)__shfl((int)v, src);
      }
  }
  const bool hi = (fg >> 1) != 0;
  u32x4 w0, w1;
#pragma unroll
  for (int a = 0; a < 2; ++a)
#pragma unroll
    for (int hh = 0; hh < 2; ++hh) {
      w0[2 * a + hh] = hi ? rcv[a ^ 1][0][hh] : rcv[a][0][hh];
      w1[2 * a + hh] = hi ? rcv[a ^ 1][1][hh] : rcv[a][1][hh];
    }
  pa[0] = __builtin_bit_cast(bf16x8, w0);
  pa[1] = __builtin_bit_cast(bf16x8, w1);
}

static __device__ __forceinline__ void write_out(
    __bf16* __restrict__ out, f32x4 (&o)[4], float l,
    int b, int hoff, int q0wt, int fg, int fr) {
  float linv = 1.f / l;
  float lo[4];
#pragma unroll
  for (int r = 0; r < 4; ++r)
    lo[r] = __shfl(linv, fg * 4 + r);
#pragma unroll
  for (int n = 0; n < 4; ++n)
#pragma unroll
    for (int r = 0; r < 4; ++r) {
      int t = q0wt + fg * 4 + r;
      out[((size_t)(b * 2048 + t)) * 1024 + hoff + n * 16 + fr] = (__bf16)(o[n][r] * lo[r]);
    }
}

// FA2-style causal flash attention: dual-bh 8-wave blocks with fused task
// pairs (uniform makespan at 16 waves/CU).
// Grid 256 x 512 threads: blk -> xcd=blk&7, pp=(blk>>3)&1, i=blk>>4 (0..15).
// Wave group grp = w>>2 picks bh = (xcd<<2)|(pp<<1)|grp; each block covers
// 2 bh x 2 qb = 4 of the 1024 (bh,qb) tasks. Wave wl = w&3 runs the dual-task
// body: qb0 = 31-i (long), qb1 = i (short, qb1 < qb0 always since i<=15),
// sharing staged K/V tiles and K/V fragment reads. Both groups iterate
// kt = 0..qb0 in lockstep (same i) -> uniform barrier schedule, ~33
// tile-units per block. 64KB LDS -> 2 blocks/CU = 16 waves/CU constant.
// Q pre-scaled by 0.125*log2(e) in GEMM1.
__global__ __launch_bounds__(512, 4)
void attn_causal13(const __bf16* __restrict__ qk, const __bf16* __restrict__ vt,
                   __bf16* __restrict__ out) {
  constexpr float NEG = -1e30f;

  __shared__ __bf16 lK[2][2][4096];  // [bhgrp][buf][key(64) x dkchunk(8) x 8]
  __shared__ __bf16 lV[2][2][4096];  // [bhgrp][buf][dk(64) x keychunk(8) x 8]

  const int tid = threadIdx.x;
  const int lane = tid & 63, w = tid >> 6;    // w in 0..7
  const int grp = w >> 2, wl = w & 3;
  const int fr = lane & 15, fg = lane >> 4;
  const int blk = blockIdx.x;
  const int xcd = blk & 7;
  const int pp = (blk >> 3) & 1;
  const int i = blk >> 4;                     // 0..15
  const int bh = (xcd << 2) | (pp << 1) | grp;
  const int qb0 = 31 - i, qb1 = i;            // long, short tasks (qb1 < qb0)
  const int b = bh >> 4, h = bh & 15;
  const int q0w0 = (qb0 << 6) + (wl << 4);
  const int q0w1 = (qb1 << 6) + (wl << 4);
  const int hoff = h * 64;
  const size_t qkbase = (size_t)b * (2048 * 2048);
  const __bf16* kb = qk + qkbase + 1024 + hoff;                // K rows, stride 2048
  const __bf16* vtb = vt + (size_t)((b << 10) | hoff) * 2048;  // V^T rows, stride 2048

  bf16x8 qf0[2], qf1[2];
#pragma unroll
  for (int c = 0; c < 2; ++c) {
    qf0[c] = ld8(qk + qkbase + (size_t)(q0w0 + fr) * 2048 + hoff + c * 32 + fg * 8);
    qf1[c] = ld8(qk + qkbase + (size_t)(q0w1 + fr) * 2048 + hoff + c * 32 + fg * 8);
  }

  f32x4 o0[4] = {}, o1[4] = {};
  float m_0 = NEG, l_0 = 0.f, m_1 = NEG, l_1 = 0.f;

  // per-group staging: 4 waves of the group stage its bh's K/V tile (8 chunks each)
#define STAGE(bf, k0s)                                                             \
  do {                                                                             \
    _Pragma("unroll")                                                              \
    for (int jj = 0; jj < 2; ++jj) {                                               \
      const int q = (wl << 1) | jj;                                                \
      const int v = (q << 6) | lane;                                               \
      const int row = v >> 3;                                                      \
      const int cc = (v & 7) ^ (row & 7);                                          \
      gld16(kb + (size_t)((k0s) + row) * 2048 + (cc << 3), &lK[grp][bf][q << 9]);  \
      gld16(vtb + (size_t)row * 2048 + (k0s) + (cc << 3), &lV[grp][bf][q << 9]);   \
    }                                                                              \
  } while (0)

  int buf = 0;
  STAGE(0, 0);
  __syncthreads();

  for (int kt = 0; kt <= qb0; ++kt) {
    const int k0 = kt << 6;
    if (kt < qb0) STAGE(buf ^ 1, k0 + 64);
    const bool act1 = (kt <= qb1);

    f32x4 s0[4] = {}, s1[4] = {};
#pragma unroll
    for (int c = 0; c < 2; ++c) {
      bf16x8 kfc[4];
#pragma unroll
      for (int n = 0; n < 4; ++n) {
        const int row = n * 16 + fr;
        const int sc = ((c << 2) | fg) ^ (row & 7);
        kfc[n] = ld8(&lK[grp][buf][(row << 6) + (sc << 3)]);
      }
#pragma unroll
      for (int n = 0; n < 4; ++n)
        s0[n] = MFMA(kfc[n], qf0[c], s0[n]);
      if (act1) {
#pragma unroll
        for (int n = 0; n < 4; ++n)
          s1[n] = MFMA(kfc[n], qf1[c], s1[n]);
      }
    }

    bf16x8 pa0[2], pa1[2];
    softmax_step(s0, o0, m_0, l_0, pa0, kt == qb0, q0w0, k0, fg, fr);
    if (act1)
      softmax_step(s1, o1, m_1, l_1, pa1, kt == qb1, q0w1, k0, fg, fr);

#pragma unroll
    for (int c = 0; c < 2; ++c) {
      bf16x8 vfc[4];
#pragma unroll
      for (int n = 0; n < 4; ++n) {
        const int row = n * 16 + fr;
        const int sc = ((c << 2) | fg) ^ (row & 7);
        vfc[n] = ld8(&lV[grp][buf][(row << 6) + (sc << 3)]);
      }
#pragma unroll
      for (int n = 0; n < 4; ++n)
        o0[n] = MFMA(pa0[c], vfc[n], o0[n]);
      if (act1) {
#pragma unroll
        for (int n = 0; n < 4; ++n)
          o1[n] = MFMA(pa1[c], vfc[n], o1[n]);
      }
    }

    __syncthreads();  // all waves done reading buf; vmcnt drained (next staged)
    buf ^= 1;
  }
#undef STAGE

  write_out(out, o0, l_0, b, hoff, q0w0, fg, fr);
  write_out(out, o1, l_1, b, hoff, q0w1, fg, fr);
}

extern "C" void kernel_launch(void* const* d_in, const int* in_sizes, int n_in,
                              void* d_out, int out_size, void* d_ws, size_t ws_size,
                              hipStream_t stream) {
  const float* x = (const float*)d_in[0];       // (2,2048,1024) fp32
  const float* w_qkv = (const float*)d_in[1];   // (3072,1024) fp32
  const float* w_o = (const float*)d_in[2];     // (1024,1024) fp32
  float* out = (float*)d_out;                   // (2,2048,1024) fp32

  const int M = 4096;  // B*T
  __bf16* qk = (__bf16*)d_ws;                                    // 4096 x 2048 bf16 (16MB)
  __bf16* vt = (__bf16*)((char*)d_ws + (size_t)M * 2048 * 2);    // 2048 x 2048 bf16 (8MB)
  __bf16* attn = (__bf16*)((char*)d_ws + (size_t)M * 3072 * 2);  // 4096 x 1024 bf16 (8MB)

  // bf16 copies of x and W_qkv live in d_out (dead until GEMM2 writes it)
  __bf16* xb = (__bf16*)d_out;
  __bf16* wqb = xb + 4194304;
  const int NX = 4194304;  // x elems

  cvt_f32_bf16<<<3584, 256, 0, stream>>>(x, xb, NX, w_qkv, wqb);

  // GEMM1: qkv = x @ W_qkv^T ; Q (pre-scaled), K -> qk, V -> vt transposed
  gemm3<128, true, true, false><<<(M / 128) * (3072 / 128), 256, 0, stream>>>(
      xb, (const void*)wqb, (void*)qk, vt, M, 3072, 1024);

  // causal attention: 256 blocks x 512 (dual-bh 8-wave pairing, 16 waves/CU)
  attn_causal13<<<256, 512, 0, stream>>>(qk, vt, attn);

  // GEMM2: out = attn @ W_o^T (BN=64 tiles: 512 blocks)
  gemm3<64, false, false, true><<<(M / 128) * (1024 / 64), 256, 0, stream>>>(
      attn, (const void*)w_o, (void*)out, nullptr, M, 1024, 1024);
}

// Round 14
// 146.392 us; speedup vs baseline: 1.1946x; 1.1946x over previous
//
#include <hip/hip_runtime.h>
#include <hip/hip_bf16.h>

typedef __bf16 bf16x8 __attribute__((ext_vector_type(8)));
typedef float f32x4 __attribute__((ext_vector_type(4)));
typedef unsigned int u32;
typedef u32 u32x4 __attribute__((ext_vector_type(4)));

#define MFMA(a, b, c) __builtin_amdgcn_mfma_f32_16x16x32_bf16((a), (b), (c), 0, 0, 0)

static __device__ __forceinline__ bf16x8 ld8(const __bf16* p) {
  return *reinterpret_cast<const bf16x8*>(p);
}

// pack two f32 -> bf16x2 in one u32 (compiler fuses to v_cvt_pk_bf16_f32)
static __device__ __forceinline__ u32 pkbf(float a, float b) {
  union { __bf16 h; unsigned short s; } x, y;
  x.h = (__bf16)a; y.h = (__bf16)b;
  return (u32)x.s | ((u32)y.s << 16);
}

// async global->LDS, 16B per lane; LDS dest is wave-uniform base + lane*16
typedef unsigned int __attribute__((address_space(1))) gu32_t;
typedef unsigned int __attribute__((address_space(3))) lu32_t;
static __device__ __forceinline__ void gld16(const __bf16* g, __bf16* l) {
  __builtin_amdgcn_global_load_lds((const gu32_t*)(const void*)g,
                                   (lu32_t*)(void*)l, 16, 0, 0);
}

// fp32 -> bf16 conversion for x and W_qkv (exact-fit into d_out region)
__global__ __launch_bounds__(256)
void cvt_f32_bf16(const float* __restrict__ a, __bf16* __restrict__ oa, int na,
                  const float* __restrict__ b, __bf16* __restrict__ ob) {
  const int i = blockIdx.x * 256 + threadIdx.x;  // one 8-elem chunk per thread
  const float* src; __bf16* dst; int e;
  if (i < (na >> 3)) { src = a; dst = oa; e = i << 3; }
  else { src = b; dst = ob; e = (i << 3) - na; }
  f32x4 v0 = *reinterpret_cast<const f32x4*>(src + e);
  f32x4 v1 = *reinterpret_cast<const f32x4*>(src + e + 4);
  bf16x8 o;
#pragma unroll
  for (int j = 0; j < 4; ++j) { o[j] = (__bf16)v0[j]; o[j + 4] = (__bf16)v1[j]; }
  *reinterpret_cast<bf16x8*>(dst + e) = o;
}

// 8 fp32 -> 8 bf16 LDS write (16B)
static __device__ __forceinline__ void stage8f(__bf16* __restrict__ dst,
                                               const float* __restrict__ src) {
  f32x4 a = *reinterpret_cast<const f32x4*>(src);
  f32x4 b = *reinterpret_cast<const f32x4*>(src + 4);
  bf16x8 o;
#pragma unroll
  for (int i = 0; i < 4; ++i) { o[i] = (__bf16)a[i]; o[i + 4] = (__bf16)b[i]; }
  *reinterpret_cast<bf16x8*>(dst) = o;
}

// C[m][n] = sum_k A[m][k] * W[n][k]  (A @ W^T).  BM=128, BK=64, BN template.
// A bf16 via global_load_lds(16B), pre-swizzled source (chunk ^= row&7).
// W: bf16 via gld16 (same swizzle) or fp32 via reg-stage + swizzled ds_write.
// 4 waves 2x2; wave tile 64 x BN/2. SPLIT (GEMM1): Q cols scaled by SC2Q;
// cols [0,2048) -> QK buf; [2048,3072) -> VT[b*1024+col-2048][t].
template<int BN, bool SPLIT, bool OUT_BF16, bool B_F32>
__global__ __launch_bounds__(256, 2)
void gemm3(const __bf16* __restrict__ A, const void* __restrict__ Wv,
           void* __restrict__ Cv, __bf16* __restrict__ VT,
           int M, int N, int K) {
  constexpr int NF = BN / 32;  // B frags per wave per kc
  constexpr float SC2Q = 0.125f * 1.4426950408889634f;
  __shared__ __bf16 lA[128 * 64];
  __shared__ __bf16 lB[BN * 64];

  const int tid = threadIdx.x;
  const int ntiles = N / BN;
  const int mt = blockIdx.x / ntiles;
  const int nt = blockIdx.x % ntiles;
  const int m0 = mt << 7, n0 = nt * BN;
  const int lane = tid & 63, w = tid >> 6;
  const int wm = (w >> 1) << 6;
  const int wn = (w & 1) * (BN / 2);
  const int fr = lane & 15, fg = lane >> 4;

  f32x4 acc[4][NF] = {};

  for (int k0 = 0; k0 < K; k0 += 64) {
    __syncthreads();
#pragma unroll
    for (int jj = 0; jj < 4; ++jj) {
      const int q = (w << 2) | jj;
      const int v = (q << 6) | lane;
      const int row = v >> 3;
      const int cc = (v & 7) ^ (row & 7);
      gld16(A + (size_t)(m0 + row) * K + k0 + (cc << 3), lA + (q << 9));
    }
    if constexpr (B_F32) {
#pragma unroll
      for (int hh = 0; hh < BN / 64; ++hh) {
        const int row = (tid >> 2) + (hh << 6);
        const int c0 = (tid & 3) << 1;
        const float* src = (const float*)Wv + (size_t)(n0 + row) * K + k0 + (c0 << 3);
#pragma unroll
        for (int cg = 0; cg < 2; ++cg)
          stage8f(lB + (row << 6) + (((c0 + cg) ^ (row & 7)) << 3), src + (cg << 3));
      }
    } else {
#pragma unroll
      for (int jj = 0; jj < NF; ++jj) {
        const int q = w * NF + jj;
        const int v = (q << 6) | lane;
        const int row = v >> 3;
        const int cc = (v & 7) ^ (row & 7);
        gld16((const __bf16*)Wv + (size_t)(n0 + row) * K + k0 + (cc << 3), lB + (q << 9));
      }
    }
    __syncthreads();

    bf16x8 af[2][4], bfr[2][NF];
#pragma unroll
    for (int kc = 0; kc < 2; ++kc) {
#pragma unroll
      for (int m = 0; m < 4; ++m) {
        const int row = wm + m * 16 + fr;
        af[kc][m] = ld8(lA + (row << 6) + ((((kc << 2) | fg) ^ (row & 7)) << 3));
      }
#pragma unroll
      for (int n = 0; n < NF; ++n) {
        const int row = wn + n * 16 + fr;
        bfr[kc][n] = ld8(lB + (row << 6) + ((((kc << 2) | fg) ^ (row & 7)) << 3));
      }
    }
#pragma unroll
    for (int kc = 0; kc < 2; ++kc)
#pragma unroll
      for (int m = 0; m < 4; ++m)
#pragma unroll
        for (int n = 0; n < NF; ++n)
          acc[m][n] = MFMA(af[kc][m], bfr[kc][n], acc[m][n]);
  }

  // C/D layout: col = lane&15, row = (lane>>4)*4 + reg
#pragma unroll
  for (int m = 0; m < 4; ++m) {
#pragma unroll
    for (int n = 0; n < NF; ++n) {
#pragma unroll
      for (int r = 0; r < 4; ++r) {
        int row = m0 + wm + m * 16 + fg * 4 + r;
        int col = n0 + wn + n * 16 + fr;
        float v = acc[m][n][r];
        if constexpr (SPLIT) {
          int b = row >> 11, t = row & 2047;
          if (col >= 2048) {
            VT[((size_t)(b << 10) + (col - 2048)) * 2048 + t] = (__bf16)v;
          } else {
            if (col < 1024) v *= SC2Q;  // pre-scale Q for attention
            ((__bf16*)Cv)[(size_t)row * 2048 + col] = (__bf16)v;
          }
        } else if constexpr (OUT_BF16) {
          ((__bf16*)Cv)[(size_t)row * N + col] = (__bf16)v;
        } else {
          ((float*)Cv)[(size_t)row * N + col] = v;
        }
      }
    }
  }
}

// One online-softmax step for a 64-key tile held as S^T fragments.
// s[n][r] = S[key=k0+n*16+fg*4+r][q=q0wt+fr] (already scaled, log2 domain).
static __device__ __forceinline__ void softmax_step(
    f32x4 (&s)[4], f32x4 (&o)[4], float& m, float& l, bf16x8 (&pa)[2],
    bool diag, int q0wt, int k0, int fg, int fr) {
  constexpr float NEG = -1e30f;
  float sv[4][4];
#pragma unroll
  for (int n = 0; n < 4; ++n)
#pragma unroll
    for (int r = 0; r < 4; ++r) {
      float x = s[n][r];
      if (diag && (k0 + n * 16 + fg * 4 + r > q0wt + fr)) x = NEG;
      sv[n][r] = x;
    }

  float t0 = fmaxf(fmaxf(sv[0][0], sv[0][1]), fmaxf(sv[0][2], sv[0][3]));
  float t1 = fmaxf(fmaxf(sv[1][0], sv[1][1]), fmaxf(sv[1][2], sv[1][3]));
  float t2 = fmaxf(fmaxf(sv[2][0], sv[2][1]), fmaxf(sv[2][2], sv[2][3]));
  float t3 = fmaxf(fmaxf(sv[3][0], sv[3][1]), fmaxf(sv[3][2], sv[3][3]));
  float rm = fmaxf(fmaxf(t0, t1), fmaxf(t2, t3));
  rm = fmaxf(rm, __shfl_xor(rm, 16));
  rm = fmaxf(rm, __shfl_xor(rm, 32));

  // defer-max (T13): rescale only when tile max pushes past m+16
  if (!__all(rm <= m + 16.f)) {
    float mnew = fmaxf(m, rm);
    float alpha = __builtin_exp2f(m - mnew);
    m = mnew;
    l *= alpha;
    float ao[4];
#pragma unroll
    for (int r = 0; r < 4; ++r)
      ao[r] = __shfl(alpha, fg * 4 + r);
#pragma unroll
    for (int n = 0; n < 4; ++n)
#pragma unroll
      for (int r = 0; r < 4; ++r)
        o[n][r] *= ao[r];
  }

  float p[4][4];
#pragma unroll
  for (int n = 0; n < 4; ++n)
#pragma unroll
    for (int r = 0; r < 4; ++r)
      p[n][r] = __builtin_exp2f(sv[n][r] - m);

  float u0 = (p[0][0] + p[0][1]) + (p[0][2] + p[0][3]);
  float u1 = (p[1][0] + p[1][1]) + (p[1][2] + p[1][3]);
  float u2 = (p[2][0] + p[2][1]) + (p[2][2] + p[2][3]);
  float u3 = (p[3][0] + p[3][1]) + (p[3][2] + p[3][3]);
  float rs = (u0 + u1) + (u2 + u3);
  rs += __shfl_xor(rs, 16);
  rs += __shfl_xor(rs, 32);
  l += rs;

  u32 wpk[4][2];
#pragma unroll
  for (int n = 0; n < 4; ++n) {
    wpk[n][0] = pkbf(p[n][0], p[n][1]);
    wpk[n][1] = pkbf(p[n][2], p[n][3]);
  }

  // redistribute P^T -> PV A-fragments (8 bpermutes; bijective instances)
  u32 rcv[2][2][2];
#pragma unroll
  for (int e = 0; e < 2; ++e) {
    const int src = fr + ((((fg & 1) << 1) | ((fg >> 1) ^ e)) << 4);
    const bool tsel = ((fg & 1) ^ e) != 0;
#pragma unroll
    for (int c = 0; c < 2; ++c)
#pragma unroll
      for (int hh = 0; hh < 2; ++hh) {
        u32 v = tsel ? wpk[(c << 1) | 1][hh] : wpk[(c << 1) | 0][hh];
        rcv[e][c][hh] = (u32)__shfl((int)v, src);
      }
  }
  const bool hi = (fg >> 1) != 0;
  u32x4 w0, w1;
#pragma unroll
  for (int a = 0; a < 2; ++a)
#pragma unroll
    for (int hh = 0; hh < 2; ++hh) {
      w0[2 * a + hh] = hi ? rcv[a ^ 1][0][hh] : rcv[a][0][hh];
      w1[2 * a + hh] = hi ? rcv[a ^ 1][1][hh] : rcv[a][1][hh];
    }
  pa[0] = __builtin_bit_cast(bf16x8, w0);
  pa[1] = __builtin_bit_cast(bf16x8, w1);
}

static __device__ __forceinline__ void write_out(
    __bf16* __restrict__ out, f32x4 (&o)[4], float l,
    int b, int hoff, int q0wt, int fg, int fr) {
  float linv = 1.f / l;
  float lo[4];
#pragma unroll
  for (int r = 0; r < 4; ++r)
    lo[r] = __shfl(linv, fg * 4 + r);
#pragma unroll
  for (int n = 0; n < 4; ++n)
#pragma unroll
    for (int r = 0; r < 4; ++r) {
      int t = q0wt + fg * 4 + r;
      out[((size_t)(b * 2048 + t)) * 1024 + hoff + n * 16 + fr] = (__bf16)(o[n][r] * lo[r]);
    }
}

// FA2-style causal flash attention: 8-wave parity-split pair blocks.
// Grid 512 x 512 threads. blk -> xcd=blk&7, bh=((blk&7)<<2)|((blk>>3)&3),
// i = blk>>5 (0..15). One bh per block; tasks qb0=31-i (long), qb1=i (short).
// Waves 0-3 (p=0) process key tiles kt=0,2,4,...; waves 4-7 (p=1) kt=1,3,...
// Each 4-wave half runs the R7/R8-validated dual-task body on its own
// double-buffered K/V LDS stream (64KB total -> 2 blocks/CU = 16 waves/CU,
// every block ~17 uniform iterations). Final flash-merge of the two parity
// partials happens in LDS (reusing the K/V buffers post-loop).
// Q pre-scaled by 0.125*log2(e) in GEMM1.
__global__ __launch_bounds__(512, 2)
void attn_causal14(const __bf16* __restrict__ qk, const __bf16* __restrict__ vt,
                   __bf16* __restrict__ out) {
  constexpr float NEG = -1e30f;

  __shared__ __bf16 lK[2][2][4096];  // [parity][buf][key(64) x dkchunk(8) x 8]
  __shared__ __bf16 lV[2][2][4096];  // [parity][buf][dk(64) x keychunk(8) x 8]

  const int tid = threadIdx.x;
  const int lane = tid & 63, w = tid >> 6;    // w in 0..7
  const int p = w >> 2, wl = w & 3;           // parity, wave-in-half
  const int fr = lane & 15, fg = lane >> 4;
  const int blk = blockIdx.x;
  const int bh = ((blk & 7) << 2) | ((blk >> 3) & 3);  // XCD-local bh group
  const int i = blk >> 5;                     // 0..15 pair index
  const int qb0 = 31 - i, qb1 = i;            // long, short tasks (qb1 < qb0)
  const int b = bh >> 4, h = bh & 15;
  const int q0w0 = (qb0 << 6) + (wl << 4);
  const int q0w1 = (qb1 << 6) + (wl << 4);
  const int hoff = h * 64;
  const size_t qkbase = (size_t)b * (2048 * 2048);
  const __bf16* kb = qk + qkbase + 1024 + hoff;                // K rows, stride 2048
  const __bf16* vtb = vt + (size_t)((b << 10) | hoff) * 2048;  // V^T rows, stride 2048

  bf16x8 qf0[2], qf1[2];
#pragma unroll
  for (int c = 0; c < 2; ++c) {
    qf0[c] = ld8(qk + qkbase + (size_t)(q0w0 + fr) * 2048 + hoff + c * 32 + fg * 8);
    qf1[c] = ld8(qk + qkbase + (size_t)(q0w1 + fr) * 2048 + hoff + c * 32 + fg * 8);
  }

  f32x4 o0[4] = {}, o1[4] = {};
  float m_0 = NEG, l_0 = 0.f, m_1 = NEG, l_1 = 0.f;

  // per-half staging: the 4 waves of parity p stage its stream's tile
#define STAGE(bf, k0s)                                                           \
  do {                                                                           \
    _Pragma("unroll")                                                            \
    for (int jj = 0; jj < 2; ++jj) {                                             \
      const int q = (wl << 1) | jj;                                              \
      const int v = (q << 6) | lane;                                             \
      const int row = v >> 3;                                                    \
      const int cc = (v & 7) ^ (row & 7);                                        \
      gld16(kb + (size_t)((k0s) + row) * 2048 + (cc << 3), &lK[p][bf][q << 9]);  \
      gld16(vtb + (size_t)row * 2048 + (k0s) + (cc << 3), &lV[p][bf][q << 9]);   \
    }                                                                            \
  } while (0)

  int buf = 0;
  STAGE(0, p << 6);  // first tile of this parity (kt = p; qb0 >= 16 > 1)
  __syncthreads();

  const int L = (qb0 >> 1) + 1;  // uniform trip count across both halves
  for (int j = 0; j < L; ++j) {
    const int kt = 2 * j + p;
    const int k0 = kt << 6;
    const int ktn = kt + 2;
    if (ktn <= qb0) STAGE(buf ^ 1, ktn << 6);
    const bool act0 = (kt <= qb0);
    const bool act1 = (kt <= qb1);

    if (act0) {
      f32x4 s0[4] = {}, s1[4] = {};
#pragma unroll
      for (int c = 0; c < 2; ++c) {
        bf16x8 kfc[4];
#pragma unroll
        for (int n = 0; n < 4; ++n) {
          const int row = n * 16 + fr;
          const int sc = ((c << 2) | fg) ^ (row & 7);
          kfc[n] = ld8(&lK[p][buf][(row << 6) + (sc << 3)]);
        }
#pragma unroll
        for (int n = 0; n < 4; ++n)
          s0[n] = MFMA(kfc[n], qf0[c], s0[n]);
        if (act1) {
#pragma unroll
          for (int n = 0; n < 4; ++n)
            s1[n] = MFMA(kfc[n], qf1[c], s1[n]);
        }
      }

      bf16x8 pa0[2], pa1[2];
      softmax_step(s0, o0, m_0, l_0, pa0, kt == qb0, q0w0, k0, fg, fr);
      if (act1)
        softmax_step(s1, o1, m_1, l_1, pa1, kt == qb1, q0w1, k0, fg, fr);

#pragma unroll
      for (int c = 0; c < 2; ++c) {
        bf16x8 vfc[4];
#pragma unroll
        for (int n = 0; n < 4; ++n) {
          const int row = n * 16 + fr;
          const int sc = ((c << 2) | fg) ^ (row & 7);
          vfc[n] = ld8(&lV[p][buf][(row << 6) + (sc << 3)]);
        }
#pragma unroll
        for (int n = 0; n < 4; ++n)
          o0[n] = MFMA(pa0[c], vfc[n], o0[n]);
        if (act1) {
#pragma unroll
          for (int n = 0; n < 4; ++n)
            o1[n] = MFMA(pa1[c], vfc[n], o1[n]);
        }
      }
    }

    __syncthreads();  // both halves advance in lockstep; LDS safe to flip
    buf ^= 1;
  }
#undef STAGE

  // ---- parity combine in LDS (K/V buffers are dead after the barrier) ----
  // Upper waves (p=1) deposit unnormalized partials; lower waves merge:
  // mstar = max(mA,mB); O = 2^(mA-mstar) OA + 2^(mB-mstar) OB; l likewise.
  float* fOb = (float*)&lK[0][0][0];  // 8 regions x 1024 f32 (32KB)
  float* fSb = (float*)&lV[0][0][0];  // 8 regions x 128 f32
  if (p == 1) {
    const int r0 = wl * 2;
#pragma unroll
    for (int n = 0; n < 4; ++n)
#pragma unroll
      for (int r = 0; r < 4; ++r) {
        fOb[(r0 + 0) * 1024 + (n * 4 + r) * 64 + lane] = o0[n][r];
        fOb[(r0 + 1) * 1024 + (n * 4 + r) * 64 + lane] = o1[n][r];
      }
    fSb[(r0 + 0) * 128 + lane * 2] = m_0;
    fSb[(r0 + 0) * 128 + lane * 2 + 1] = l_0;
    fSb[(r0 + 1) * 128 + lane * 2] = m_1;
    fSb[(r0 + 1) * 128 + lane * 2 + 1] = l_1;
  }
  __syncthreads();
  if (p == 0) {
    const int r0 = wl * 2;
    // task 0 (long)
    {
      float mB = fSb[r0 * 128 + lane * 2];
      float lB = fSb[r0 * 128 + lane * 2 + 1];
      float ms = fmaxf(m_0, mB);
      float wA = __builtin_exp2f(m_0 - ms), wB = __builtin_exp2f(mB - ms);
      l_0 = wA * l_0 + wB * lB;
      float aA[4], aB[4];
#pragma unroll
      for (int r = 0; r < 4; ++r) {
        aA[r] = __shfl(wA, fg * 4 + r);
        aB[r] = __shfl(wB, fg * 4 + r);
      }
#pragma unroll
      for (int n = 0; n < 4; ++n)
#pragma unroll
        for (int r = 0; r < 4; ++r)
          o0[n][r] = aA[r] * o0[n][r] + aB[r] * fOb[r0 * 1024 + (n * 4 + r) * 64 + lane];
      write_out(out, o0, l_0, b, hoff, q0w0, fg, fr);
    }
    // task 1 (short)
    {
      float mB = fSb[(r0 + 1) * 128 + lane * 2];
      float lB = fSb[(r0 + 1) * 128 + lane * 2 + 1];
      float ms = fmaxf(m_1, mB);
      float wA = __builtin_exp2f(m_1 - ms), wB = __builtin_exp2f(mB - ms);
      l_1 = wA * l_1 + wB * lB;
      float aA[4], aB[4];
#pragma unroll
      for (int r = 0; r < 4; ++r) {
        aA[r] = __shfl(wA, fg * 4 + r);
        aB[r] = __shfl(wB, fg * 4 + r);
      }
#pragma unroll
      for (int n = 0; n < 4; ++n)
#pragma unroll
        for (int r = 0; r < 4; ++r)
          o1[n][r] = aA[r] * o1[n][r] + aB[r] * fOb[(r0 + 1) * 1024 + (n * 4 + r) * 64 + lane];
      write_out(out, o1, l_1, b, hoff, q0w1, fg, fr);
    }
  }
}

extern "C" void kernel_launch(void* const* d_in, const int* in_sizes, int n_in,
                              void* d_out, int out_size, void* d_ws, size_t ws_size,
                              hipStream_t stream) {
  const float* x = (const float*)d_in[0];       // (2,2048,1024) fp32
  const float* w_qkv = (const float*)d_in[1];   // (3072,1024) fp32
  const float* w_o = (const float*)d_in[2];     // (1024,1024) fp32
  float* out = (float*)d_out;                   // (2,2048,1024) fp32

  const int M = 4096;  // B*T
  __bf16* qk = (__bf16*)d_ws;                                    // 4096 x 2048 bf16 (16MB)
  __bf16* vt = (__bf16*)((char*)d_ws + (size_t)M * 2048 * 2);    // 2048 x 2048 bf16 (8MB)
  __bf16* attn = (__bf16*)((char*)d_ws + (size_t)M * 3072 * 2);  // 4096 x 1024 bf16 (8MB)

  // bf16 copies of x and W_qkv live in d_out (dead until GEMM2 writes it)
  __bf16* xb = (__bf16*)d_out;
  __bf16* wqb = xb + 4194304;
  const int NX = 4194304;  // x elems

  cvt_f32_bf16<<<3584, 256, 0, stream>>>(x, xb, NX, w_qkv, wqb);

  // GEMM1: qkv = x @ W_qkv^T ; Q (pre-scaled), K -> qk, V -> vt transposed
  gemm3<128, true, true, false><<<(M / 128) * (3072 / 128), 256, 0, stream>>>(
      xb, (const void*)wqb, (void*)qk, vt, M, 3072, 1024);

  // causal attention: 512 blocks x 512 (parity-split pair blocks, 16 waves/CU)
  attn_causal14<<<512, 512, 0, stream>>>(qk, vt, attn);

  // GEMM2: out = attn @ W_o^T (BN=64 tiles: 512 blocks)
  gemm3<64, false, false, true><<<(M / 128) * (1024 / 64), 256, 0, stream>>>(
      attn, (const void*)w_o, (void*)out, nullptr, M, 1024, 1024);
}

// Round 15
// 119.172 us; speedup vs baseline: 1.4674x; 1.2284x over previous
//
#include <hip/hip_runtime.h>
#include <hip/hip_bf16.h>

typedef __bf16 bf16x8 __attribute__((ext_vector_type(8)));
typedef float f32x4 __attribute__((ext_vector_type(4)));
typedef unsigned int u32;
typedef u32 u32x4 __attribute__((ext_vector_type(4)));

#define MFMA(a, b, c) __builtin_amdgcn_mfma_f32_16x16x32_bf16((a), (b), (c), 0, 0, 0)

static __device__ __forceinline__ bf16x8 ld8(const __bf16* p) {
  return *reinterpret_cast<const bf16x8*>(p);
}

// pack two f32 -> bf16x2 in one u32 (compiler fuses to v_cvt_pk_bf16_f32)
static __device__ __forceinline__ u32 pkbf(float a, float b) {
  union { __bf16 h; unsigned short s; } x, y;
  x.h = (__bf16)a; y.h = (__bf16)b;
  return (u32)x.s | ((u32)y.s << 16);
}

// async global->LDS, 16B per lane; LDS dest is wave-uniform base + lane*16
typedef unsigned int __attribute__((address_space(1))) gu32_t;
typedef unsigned int __attribute__((address_space(3))) lu32_t;
static __device__ __forceinline__ void gld16(const __bf16* g, __bf16* l) {
  __builtin_amdgcn_global_load_lds((const gu32_t*)(const void*)g,
                                   (lu32_t*)(void*)l, 16, 0, 0);
}

// fp32 -> bf16 conversion for x and W_qkv (exact-fit into d_out region)
__global__ __launch_bounds__(256)
void cvt_f32_bf16(const float* __restrict__ a, __bf16* __restrict__ oa, int na,
                  const float* __restrict__ b, __bf16* __restrict__ ob) {
  const int i = blockIdx.x * 256 + threadIdx.x;  // one 8-elem chunk per thread
  const float* src; __bf16* dst; int e;
  if (i < (na >> 3)) { src = a; dst = oa; e = i << 3; }
  else { src = b; dst = ob; e = (i << 3) - na; }
  f32x4 v0 = *reinterpret_cast<const f32x4*>(src + e);
  f32x4 v1 = *reinterpret_cast<const f32x4*>(src + e + 4);
  bf16x8 o;
#pragma unroll
  for (int j = 0; j < 4; ++j) { o[j] = (__bf16)v0[j]; o[j + 4] = (__bf16)v1[j]; }
  *reinterpret_cast<bf16x8*>(dst + e) = o;
}

// 8 fp32 -> 8 bf16 LDS write (16B)
static __device__ __forceinline__ void stage8f(__bf16* __restrict__ dst,
                                               const float* __restrict__ src) {
  f32x4 a = *reinterpret_cast<const f32x4*>(src);
  f32x4 b = *reinterpret_cast<const f32x4*>(src + 4);
  bf16x8 o;
#pragma unroll
  for (int i = 0; i < 4; ++i) { o[i] = (__bf16)a[i]; o[i + 4] = (__bf16)b[i]; }
  *reinterpret_cast<bf16x8*>(dst) = o;
}

// C[m][n] = sum_k A[m][k] * W[n][k]  (A @ W^T).  BM=128, BK=64, BN template.
// A bf16 via global_load_lds(16B), pre-swizzled source (chunk ^= row&7).
// W: bf16 via gld16 (same swizzle) or fp32 via reg-stage + swizzled ds_write.
// 4 waves 2x2; wave tile 64 x BN/2. XCD-aware bijective block swizzle
// (grid%8==0): panel-sharing blocks land on the same XCD L2.
// SPLIT (GEMM1): Q cols scaled by SC2Q;
// cols [0,2048) -> QK buf; [2048,3072) -> VT[b*1024+col-2048][t].
template<int BN, bool SPLIT, bool OUT_BF16, bool B_F32>
__global__ __launch_bounds__(256, 2)
void gemm3(const __bf16* __restrict__ A, const void* __restrict__ Wv,
           void* __restrict__ Cv, __bf16* __restrict__ VT,
           int M, int N, int K) {
  constexpr int NF = BN / 32;  // B frags per wave per kc
  constexpr float SC2Q = 0.125f * 1.4426950408889634f;
  __shared__ __bf16 lA[128 * 64];
  __shared__ __bf16 lB[BN * 64];

  const int tid = threadIdx.x;
  const int ntiles = N / BN;
  // XCD-aware bijective swizzle (T1): valid because gridDim.x % 8 == 0
  const int per = gridDim.x >> 3;
  const int bid = (blockIdx.x & 7) * per + (blockIdx.x >> 3);
  const int mt = bid / ntiles;
  const int nt = bid % ntiles;
  const int m0 = mt << 7, n0 = nt * BN;
  const int lane = tid & 63, w = tid >> 6;
  const int wm = (w >> 1) << 6;
  const int wn = (w & 1) * (BN / 2);
  const int fr = lane & 15, fg = lane >> 4;

  f32x4 acc[4][NF] = {};

  for (int k0 = 0; k0 < K; k0 += 64) {
    __syncthreads();
#pragma unroll
    for (int jj = 0; jj < 4; ++jj) {
      const int q = (w << 2) | jj;
      const int v = (q << 6) | lane;
      const int row = v >> 3;
      const int cc = (v & 7) ^ (row & 7);
      gld16(A + (size_t)(m0 + row) * K + k0 + (cc << 3), lA + (q << 9));
    }
    if constexpr (B_F32) {
#pragma unroll
      for (int hh = 0; hh < BN / 64; ++hh) {
        const int row = (tid >> 2) + (hh << 6);
        const int c0 = (tid & 3) << 1;
        const float* src = (const float*)Wv + (size_t)(n0 + row) * K + k0 + (c0 << 3);
#pragma unroll
        for (int cg = 0; cg < 2; ++cg)
          stage8f(lB + (row << 6) + (((c0 + cg) ^ (row & 7)) << 3), src + (cg << 3));
      }
    } else {
#pragma unroll
      for (int jj = 0; jj < NF; ++jj) {
        const int q = w * NF + jj;
        const int v = (q << 6) | lane;
        const int row = v >> 3;
        const int cc = (v & 7) ^ (row & 7);
        gld16((const __bf16*)Wv + (size_t)(n0 + row) * K + k0 + (cc << 3), lB + (q << 9));
      }
    }
    __syncthreads();

    bf16x8 af[2][4], bfr[2][NF];
#pragma unroll
    for (int kc = 0; kc < 2; ++kc) {
#pragma unroll
      for (int m = 0; m < 4; ++m) {
        const int row = wm + m * 16 + fr;
        af[kc][m] = ld8(lA + (row << 6) + ((((kc << 2) | fg) ^ (row & 7)) << 3));
      }
#pragma unroll
      for (int n = 0; n < NF; ++n) {
        const int row = wn + n * 16 + fr;
        bfr[kc][n] = ld8(lB + (row << 6) + ((((kc << 2) | fg) ^ (row & 7)) << 3));
      }
    }
#pragma unroll
    for (int kc = 0; kc < 2; ++kc)
#pragma unroll
      for (int m = 0; m < 4; ++m)
#pragma unroll
        for (int n = 0; n < NF; ++n)
          acc[m][n] = MFMA(af[kc][m], bfr[kc][n], acc[m][n]);
  }

  // C/D layout: col = lane&15, row = (lane>>4)*4 + reg
#pragma unroll
  for (int m = 0; m < 4; ++m) {
#pragma unroll
    for (int n = 0; n < NF; ++n) {
#pragma unroll
      for (int r = 0; r < 4; ++r) {
        int row = m0 + wm + m * 16 + fg * 4 + r;
        int col = n0 + wn + n * 16 + fr;
        float v = acc[m][n][r];
        if constexpr (SPLIT) {
          int b = row >> 11, t = row & 2047;
          if (col >= 2048) {
            VT[((size_t)(b << 10) + (col - 2048)) * 2048 + t] = (__bf16)v;
          } else {
            if (col < 1024) v *= SC2Q;  // pre-scale Q for attention
            ((__bf16*)Cv)[(size_t)row * 2048 + col] = (__bf16)v;
          }
        } else if constexpr (OUT_BF16) {
          ((__bf16*)Cv)[(size_t)row * N + col] = (__bf16)v;
        } else {
          ((float*)Cv)[(size_t)row * N + col] = v;
        }
      }
    }
  }
}

// One online-softmax step for a 64-key tile held as S^T fragments.
// s[n][r] = S[key=k0+n*16+fg*4+r][q=q0wt+fr] (already scaled, log2 domain).
static __device__ __forceinline__ void softmax_step(
    f32x4 (&s)[4], f32x4 (&o)[4], float& m, float& l, bf16x8 (&pa)[2],
    bool diag, int q0wt, int k0, int fg, int fr) {
  constexpr float NEG = -1e30f;
  float sv[4][4];
#pragma unroll
  for (int n = 0; n < 4; ++n)
#pragma unroll
    for (int r = 0; r < 4; ++r) {
      float x = s[n][r];
      if (diag && (k0 + n * 16 + fg * 4 + r > q0wt + fr)) x = NEG;
      sv[n][r] = x;
    }

  float t0 = fmaxf(fmaxf(sv[0][0], sv[0][1]), fmaxf(sv[0][2], sv[0][3]));
  float t1 = fmaxf(fmaxf(sv[1][0], sv[1][1]), fmaxf(sv[1][2], sv[1][3]));
  float t2 = fmaxf(fmaxf(sv[2][0], sv[2][1]), fmaxf(sv[2][2], sv[2][3]));
  float t3 = fmaxf(fmaxf(sv[3][0], sv[3][1]), fmaxf(sv[3][2], sv[3][3]));
  float rm = fmaxf(fmaxf(t0, t1), fmaxf(t2, t3));
  rm = fmaxf(rm, __shfl_xor(rm, 16));
  rm = fmaxf(rm, __shfl_xor(rm, 32));

  // defer-max (T13): rescale only when tile max pushes past m+16
  if (!__all(rm <= m + 16.f)) {
    float mnew = fmaxf(m, rm);
    float alpha = __builtin_exp2f(m - mnew);
    m = mnew;
    l *= alpha;
    float ao[4];
#pragma unroll
    for (int r = 0; r < 4; ++r)
      ao[r] = __shfl(alpha, fg * 4 + r);
#pragma unroll
    for (int n = 0; n < 4; ++n)
#pragma unroll
      for (int r = 0; r < 4; ++r)
        o[n][r] *= ao[r];
  }

  float p[4][4];
#pragma unroll
  for (int n = 0; n < 4; ++n)
#pragma unroll
    for (int r = 0; r < 4; ++r)
      p[n][r] = __builtin_exp2f(sv[n][r] - m);

  float u0 = (p[0][0] + p[0][1]) + (p[0][2] + p[0][3]);
  float u1 = (p[1][0] + p[1][1]) + (p[1][2] + p[1][3]);
  float u2 = (p[2][0] + p[2][1]) + (p[2][2] + p[2][3]);
  float u3 = (p[3][0] + p[3][1]) + (p[3][2] + p[3][3]);
  float rs = (u0 + u1) + (u2 + u3);
  rs += __shfl_xor(rs, 16);
  rs += __shfl_xor(rs, 32);
  l += rs;

  u32 wpk[4][2];
#pragma unroll
  for (int n = 0; n < 4; ++n) {
    wpk[n][0] = pkbf(p[n][0], p[n][1]);
    wpk[n][1] = pkbf(p[n][2], p[n][3]);
  }

  // redistribute P^T -> PV A-fragments (8 bpermutes; bijective instances)
  u32 rcv[2][2][2];
#pragma unroll
  for (int e = 0; e < 2; ++e) {
    const int src = fr + ((((fg & 1) << 1) | ((fg >> 1) ^ e)) << 4);
    const bool tsel = ((fg & 1) ^ e) != 0;
#pragma unroll
    for (int c = 0; c < 2; ++c)
#pragma unroll
      for (int hh = 0; hh < 2; ++hh) {
        u32 v = tsel ? wpk[(c << 1) | 1][hh] : wpk[(c << 1) | 0][hh];
        rcv[e][c][hh] = (u32)__shfl((int)v, src);
      }
  }
  const bool hi = (fg >> 1) != 0;
  u32x4 w0, w1;
#pragma unroll
  for (int a = 0; a < 2; ++a)
#pragma unroll
    for (int hh = 0; hh < 2; ++hh) {
      w0[2 * a + hh] = hi ? rcv[a ^ 1][0][hh] : rcv[a][0][hh];
      w1[2 * a + hh] = hi ? rcv[a ^ 1][1][hh] : rcv[a][1][hh];
    }
  pa[0] = __builtin_bit_cast(bf16x8, w0);
  pa[1] = __builtin_bit_cast(bf16x8, w1);
}

static __device__ __forceinline__ void write_out(
    __bf16* __restrict__ out, f32x4 (&o)[4], float l,
    int b, int hoff, int q0wt, int fg, int fr) {
  float linv = 1.f / l;
  float lo[4];
#pragma unroll
  for (int r = 0; r < 4; ++r)
    lo[r] = __shfl(linv, fg * 4 + r);
#pragma unroll
  for (int n = 0; n < 4; ++n)
#pragma unroll
    for (int r = 0; r < 4; ++r) {
      int t = q0wt + fg * 4 + r;
      out[((size_t)(b * 2048 + t)) * 1024 + hoff + n * 16 + fr] = (__bf16)(o[n][r] * lo[r]);
    }
}

// FA2-style causal flash attention (R10-proven schedule; Q pre-scaled).
// qk: (B*T, 2048) bf16, col = s(0=Q,1=K)*1024 + h*64 + dk (Q pre-scaled).
// vt: (B*1024, 2048) bf16 = V^T per (b,h): row b*1024 + h*64 + dk, col = t.
// Grid: 1024 blocks x 256. Block = (qb, bh): 64 q-rows, wave w owns rows
// [qb*64 + w*16, +16). K/V^T tiles (64x64 each) double-buffered in LDS via
// global_load_lds, chunk-XOR swizzled. One __syncthreads per tile;
// STAGE(next) issued before compute. In-register softmax via swapped QK^T.
__global__ __launch_bounds__(256, 4)
void attn_causal10(const __bf16* __restrict__ qk, const __bf16* __restrict__ vt,
                   __bf16* __restrict__ out) {
  constexpr float NEG = -1e30f;

  __shared__ __bf16 lK[2][4096];  // [buf][key(64) x dkchunk(8) x 8]
  __shared__ __bf16 lV[2][4096];  // [buf][dk(64) x keychunk(8) x 8]

  const int tid = threadIdx.x;
  const int lane = tid & 63, w = tid >> 6;
  const int fr = lane & 15, fg = lane >> 4;
  const int blk = blockIdx.x;
  const int j = blk >> 3;
  const int bh = ((blk & 7) << 2) | (j & 3);  // XCD-local bh group
  const int qb = 31 - (j >> 2);               // LPT: longest first
  const int b = bh >> 4, h = bh & 15;
  const int q0w = (qb << 6) + (w << 4);       // this wave's q base
  const int hoff = h * 64;
  const size_t qkbase = (size_t)b * (2048 * 2048);
  const __bf16* kb = qk + qkbase + 1024 + hoff;                // K rows, stride 2048
  const __bf16* vtb = vt + (size_t)((b << 10) | hoff) * 2048;  // V^T rows, stride 2048

  // Q fragments (B-operand): col = fr = q-row, k = c*32 + fg*8 + i
  bf16x8 qf[2];
#pragma unroll
  for (int c = 0; c < 2; ++c)
    qf[c] = ld8(qk + qkbase + (size_t)(q0w + fr) * 2048 + hoff + c * 32 + fg * 8);

  f32x4 o[4] = {};
  float m = NEG;
  float l = 0.f;

#define STAGE(bf, k0s)                                                        \
  do {                                                                        \
    _Pragma("unroll")                                                         \
    for (int jj = 0; jj < 2; ++jj) {                                          \
      const int q = (w << 1) | jj;                                            \
      const int v = (q << 6) | lane;                                          \
      const int row = v >> 3;                                                 \
      const int cc = (v & 7) ^ (row & 7);                                     \
      gld16(kb + (size_t)((k0s) + row) * 2048 + (cc << 3), &lK[bf][q << 9]);  \
      gld16(vtb + (size_t)row * 2048 + (k0s) + (cc << 3), &lV[bf][q << 9]);   \
    }                                                                         \
  } while (0)

  int buf = 0;
  STAGE(0, 0);
  __syncthreads();

  for (int kt = 0; kt <= qb; ++kt) {
    const int k0 = kt << 6;
    if (kt < qb) STAGE(buf ^ 1, k0 + 64);  // prefetch next tile (other buffer)

    // QK on LDS K: s[n][r] = S[key=k0+n*16+fg*4+r][q=q0w+fr] (pre-scaled)
    f32x4 s[4] = {};
#pragma unroll
    for (int c = 0; c < 2; ++c) {
      bf16x8 kfc[4];
#pragma unroll
      for (int n = 0; n < 4; ++n) {
        const int row = n * 16 + fr;
        const int sc = ((c << 2) | fg) ^ (row & 7);
        kfc[n] = ld8(&lK[buf][(row << 6) + (sc << 3)]);
      }
#pragma unroll
      for (int n = 0; n < 4; ++n)
        s[n] = MFMA(kfc[n], qf[c], s[n]);
    }

    bf16x8 pa[2];
    softmax_step(s, o, m, l, pa, kt == qb, q0w, k0, fg, fr);

    // O += P V from LDS V^T: B-frag row = dk = n*16+fr, key chunk = c*4+fg
#pragma unroll
    for (int c = 0; c < 2; ++c) {
      bf16x8 vfc[4];
#pragma unroll
      for (int n = 0; n < 4; ++n) {
        const int row = n * 16 + fr;
        const int sc = ((c << 2) | fg) ^ (row & 7);
        vfc[n] = ld8(&lV[buf][(row << 6) + (sc << 3)]);
      }
#pragma unroll
      for (int n = 0; n < 4; ++n)
        o[n] = MFMA(pa[c], vfc[n], o[n]);
    }

    __syncthreads();  // all waves done reading buf; vmcnt drained (next staged)
    buf ^= 1;
  }
#undef STAGE

  write_out(out, o, l, b, hoff, q0w, fg, fr);
}

extern "C" void kernel_launch(void* const* d_in, const int* in_sizes, int n_in,
                              void* d_out, int out_size, void* d_ws, size_t ws_size,
                              hipStream_t stream) {
  const float* x = (const float*)d_in[0];       // (2,2048,1024) fp32
  const float* w_qkv = (const float*)d_in[1];   // (3072,1024) fp32
  const float* w_o = (const float*)d_in[2];     // (1024,1024) fp32
  float* out = (float*)d_out;                   // (2,2048,1024) fp32

  const int M = 4096;  // B*T
  __bf16* qk = (__bf16*)d_ws;                                    // 4096 x 2048 bf16 (16MB)
  __bf16* vt = (__bf16*)((char*)d_ws + (size_t)M * 2048 * 2);    // 2048 x 2048 bf16 (8MB)
  __bf16* attn = (__bf16*)((char*)d_ws + (size_t)M * 3072 * 2);  // 4096 x 1024 bf16 (8MB)

  // bf16 copies of x and W_qkv live in d_out (dead until GEMM2 writes it)
  __bf16* xb = (__bf16*)d_out;
  __bf16* wqb = xb + 4194304;
  const int NX = 4194304;  // x elems

  cvt_f32_bf16<<<3584, 256, 0, stream>>>(x, xb, NX, w_qkv, wqb);

  // GEMM1: qkv = x @ W_qkv^T ; Q (pre-scaled), K -> qk, V -> vt transposed
  gemm3<128, true, true, false><<<(M / 128) * (3072 / 128), 256, 0, stream>>>(
      xb, (const void*)wqb, (void*)qk, vt, M, 3072, 1024);

  // causal attention (R10-proven schedule, pre-scaled Q)
  attn_causal10<<<1024, 256, 0, stream>>>(qk, vt, attn);

  // GEMM2: out = attn @ W_o^T (BN=64 tiles: 512 blocks)
  gemm3<64, false, false, true><<<(M / 128) * (1024 / 64), 256, 0, stream>>>(
      attn, (const void*)w_o, (void*)out, nullptr, M, 1024, 1024);
}